// Round 17
// baseline (449.666 us; speedup 1.0000x reference)
//
#include <hip/hip_runtime.h>
#include <hip/hip_bf16.h>
#include <math.h>

// ---------------- problem constants ----------------
#define BSZ   8
#define LSEQ  107
#define NNF   17
#define NEF   9
#define NH    128
#define EHD   32
#define H3D   32
#define NLAY  10
#define PCD   32
#define TLAY  3
#define THD   8
#define FFD   256
#define NCLS  3
#define DD    160          // NH + PC
#define HDD   20           // D / TH
#define NND   856          // nodes
#define NPAD  896          // padded to 14*64
#define NE    2896         // edges
#define CSTR  32           // CSR bucket stride (max in-degree bound)
#define QKVP  512          // padded qkv width
#define PRJP  192          // padded proj/ffn2 width
#define KTOT  1408         // 10*128 (rank-10 A) + 128 (root)
#define ALD2  1416         // padded LDS k-stride (bf16)

// k_setup block partition
#define SB_CHEB 428
#define SB_PAD  (SB_CHEB)          // 428: zero zA/zB pad rows
#define SB_CSR1 (SB_PAD + 1)       // 429: single-block packed-CSR build (src + weights)
#define SB_TPK  (SB_CSR1 + 1)      // 430: transformer weight pack (R9-validated)
#define NTPK    171
#define SB_BIAS (SB_TPK + NTPK)    // 601
#define SB_WT   (SB_BIAS + 1)      // 602: W-tilde pack v2 (R11-validated)
#define NWT     160                // 10 layers x 16 io-chunks
#define SB_TOT  (SB_WT + NWT)      // 762

typedef __bf16 bf16;
typedef __bf16 bf16x2 __attribute__((ext_vector_type(2)));
typedef __bf16 bf16x8 __attribute__((ext_vector_type(8)));
typedef float  f32x4  __attribute__((ext_vector_type(4)));

__device__ __forceinline__ float geluf(float z) {
    return 0.5f * z * (1.0f + erff(z * 0.70710678118654752f));
}
__device__ __forceinline__ float wred(float v) {
    #pragma unroll
    for (int o = 32; o; o >>= 1) v += __shfl_xor(v, o, 64);
    return v;
}
__device__ __forceinline__ float dinv_path(int n) {
    return (n == 0 || n == LSEQ - 1) ? 1.0f : 0.70710678118654752f;
}

// ================= k_setup (R13/R14-validated, unchanged) =================
__global__ __launch_bounds__(256) void k_setup(
        const float* __restrict__ x, const float* __restrict__ cw,
        const float* __restrict__ cb, bf16* __restrict__ zA, bf16* __restrict__ zB,
        const float* __restrict__ eattr, const float* __restrict__ eew,
        const float* __restrict__ eeb, const float* __restrict__ w1,
        const float* __restrict__ b1,
        const float* __restrict__ w2, const float* __restrict__ b2,
        const float* __restrict__ rootw, bf16* __restrict__ bpk,
        const int* __restrict__ ei, int* __restrict__ deg,
        int* __restrict__ csrs, float* __restrict__ csrw,
        const float* __restrict__ ain_w, const float* __restrict__ aow,
        const float* __restrict__ ffw1, const float* __restrict__ ffw2,
        const float* __restrict__ ain_b, const float* __restrict__ aob,
        const float* __restrict__ ffb1, const float* __restrict__ ffb2,
        bf16* __restrict__ bqkv, bf16* __restrict__ bproj,
        bf16* __restrict__ bff1, bf16* __restrict__ bff2,
        float* __restrict__ tb_bias) {
    __shared__ __align__(16) char sm[24576];
    int blk = blockIdx.x, tid = threadIdx.x;
    if (blk < SB_CHEB) {
        float (*xs)[5][NNF] = (float (*)[5][NNF])sm;
        int s = tid >> 7, o = tid & 127;
        int n = blk * 2 + s;
        int g = n / LSEQ, i = n - g * LSEQ;
        if (o < 5 * NNF) {
            int k = o / NNF, f = o - k * NNF;
            int p = i - 2 + k; p = p < 0 ? 0 : (p > LSEQ - 1 ? LSEQ - 1 : p);
            xs[s][k][f] = x[(g * LSEQ + p) * NNF + f];
        }
        __syncthreads();
        float di  = dinv_path(i);
        float dm1 = dinv_path(i - 1 < 0 ? 0 : i - 1);
        float dp1 = dinv_path(i + 1 > LSEQ - 1 ? LSEQ - 1 : i + 1);
        float dm2 = dinv_path(i - 2 < 0 ? 0 : i - 2);
        float dp2 = dinv_path(i + 2 > LSEQ - 1 ? LSEQ - 1 : i + 2);
        float wmc = (i > 0)        ? -(dm1 * di) : 0.f;
        float wpc = (i < LSEQ - 1) ? -(dp1 * di) : 0.f;
        float wmm = (i - 1 > 0)        ? -(dm2 * dm1) : 0.f;
        float wpm = -(di * dm1);
        float wmp = -(di * dp1);
        float wpp = (i + 1 < LSEQ - 1) ? -(dp2 * dp1) : 0.f;
        float acc = cb[o];
        #pragma unroll
        for (int f = 0; f < NNF; ++f) {
            float xm2 = xs[s][0][f], xm1 = xs[s][1][f], x0 = xs[s][2][f],
                  xp1 = xs[s][3][f], xp2 = xs[s][4][f];
            float t1c = wmc * xm1 + wpc * xp1;
            float t1m = wmm * xm2 + wpm * x0;
            float t1p = wmp * x0 + wpp * xp2;
            float t2 = 2.f * (wmc * t1m + wpc * t1p) - x0;
            acc += x0 * cw[f * NH + o] + t1c * cw[(NNF + f) * NH + o]
                 + t2 * cw[(2 * NNF + f) * NH + o];
        }
        zA[n * NH + o] = (bf16)acc;
    } else if (blk == SB_PAD) {
        for (int i = tid; i < (NPAD - NND) * NH; i += 256) {
            zA[NND * NH + i] = (bf16)0.f;
            zB[NND * NH + i] = (bf16)0.f;
        }
    } else if (blk == SB_CSR1) {
        int* ldeg = (int*)sm;
        for (int i = tid; i < NND; i += 256) ldeg[i] = 0;
        __syncthreads();
        for (int e = tid; e < NE; e += 256) {
            int d = ei[NE + e];
            int slot = atomicAdd(&ldeg[d], 1);
            if (slot < CSTR) {
                int idx = d * CSTR + slot;
                csrs[idx] = ei[e];
                float* wp = csrw + (size_t)idx * 10;
                #pragma unroll
                for (int f = 0; f < NEF; ++f) wp[f] = eattr[e * NEF + f];
                wp[9] = 1.0f;
            }
        }
        __syncthreads();
        for (int i = tid; i < NND; i += 256) deg[i] = ldeg[i];
    } else if (blk < SB_BIAS) {
        bf16 (*tt)[65] = (bf16 (*)[65])sm;
        int v = blk - SB_TPK;
        int tl = v / 57, t = v % 57;
        const float* src; bf16* dst; int Kd, srcN, ct, kt;
        if (t < 24)      { ct = t & 7;  kt = t >> 3;          src = ain_w + (size_t)tl * DD * 3 * DD; srcN = 3 * DD; Kd = DD;  dst = bqkv  + (size_t)tl * QKVP * DD; }
        else if (t < 33) { int u = t - 24; ct = u % 3; kt = u / 3; src = aow + (size_t)tl * DD * DD;  srcN = DD;     Kd = DD;  dst = bproj + (size_t)tl * PRJP * DD; }
        else if (t < 45) { int u = t - 33; ct = u % 4; kt = u / 4; src = ffw1 + (size_t)tl * DD * FFD; srcN = FFD;   Kd = DD;  dst = bff1  + (size_t)tl * FFD * DD; }
        else             { int u = t - 45; ct = u % 3; kt = u / 3; src = ffw2 + (size_t)tl * FFD * DD; srcN = DD;    Kd = FFD; dst = bff2  + (size_t)tl * PRJP * FFD; }
        int cc = tid & 63, rr = tid >> 6;
        #pragma unroll
        for (int rep = 0; rep < 16; ++rep) {
            int kl = rep * 4 + rr;
            int k = kt * 64 + kl;
            int col = ct * 64 + cc;
            float val = (k < Kd && col < srcN) ? src[(size_t)k * srcN + col] : 0.f;
            tt[kl][cc] = (bf16)val;
        }
        __syncthreads();
        int k = kt * 64 + cc;
        if (k < Kd) {
            #pragma unroll
            for (int rep = 0; rep < 16; ++rep) {
                int c = rep * 4 + rr;
                dst[(size_t)(ct * 64 + c) * Kd + k] = tt[cc][c];
            }
        }
    } else if (blk == SB_BIAS) {
        for (int i = tid; i < 3 * 1152; i += 256) {
            int tl = i / 1152, r = i % 1152;
            float val;
            if (r < 512)      { val = (r < 480) ? ain_b[tl * 480 + r] : 0.f; }
            else if (r < 704) { int c = r - 512; val = (c < 160) ? aob[tl * 160 + c] : 0.f; }
            else if (r < 960) { int c = r - 704; val = ffb1[tl * 256 + c]; }
            else              { int c = r - 960; val = (c < 160) ? ffb2[tl * 160 + c] : 0.f; }
            tb_bias[i] = val;
        }
    } else {
        float* gw  = (float*)sm;               // [10][32]
        bf16* ldsT = (bf16*)(sm + 2048);       // [11][128][8]
        int v = blk - SB_WT;
        int l = v >> 4, chunk = v & 15;
        int io0 = chunk * 1024;
        for (int e = tid; e < 320; e += 256) {
            int f = e >> 5, j = e & 31;
            float acc;
            if (f < 9) {
                acc = 0.f;
                for (int m = 0; m < EHD; ++m)
                    acc += eew[f * EHD + m] * w1[(size_t)l * EHD * H3D + m * H3D + j];
            } else {
                acc = b1[l * H3D + j];
                for (int m = 0; m < EHD; ++m)
                    acc += eeb[m] * w1[(size_t)l * EHD * H3D + m * H3D + j];
            }
            gw[e] = acc;
        }
        __syncthreads();
        int io = io0 + tid * 4;
        const float* w2l = w2 + (size_t)l * 524288;
        float acc[10][4];
        float4 b2v = *(const float4*)(b2 + (size_t)l * 16384 + io);
        #pragma unroll
        for (int f = 0; f < 9; ++f) { acc[f][0] = 0.f; acc[f][1] = 0.f; acc[f][2] = 0.f; acc[f][3] = 0.f; }
        acc[9][0] = b2v.x; acc[9][1] = b2v.y; acc[9][2] = b2v.z; acc[9][3] = b2v.w;
        for (int j = 0; j < H3D; ++j) {
            float4 wv4 = *(const float4*)(w2l + (size_t)j * 16384 + io);
            #pragma unroll
            for (int f = 0; f < 10; ++f) {
                float gf = gw[f * 32 + j];
                acc[f][0] += gf * wv4.x; acc[f][1] += gf * wv4.y;
                acc[f][2] += gf * wv4.z; acc[f][3] += gf * wv4.w;
            }
        }
        int o4 = (tid & 31) * 4, il = tid >> 5;
        #pragma unroll
        for (int f = 0; f < 10; ++f)
            #pragma unroll
            for (int k = 0; k < 4; ++k)
                ldsT[(f * 128 + o4 + k) * 8 + il] = (bf16)acc[f][k];
        float4 rv = *(const float4*)(rootw + (size_t)l * 16384 + io);
        ldsT[(10 * 128 + o4 + 0) * 8 + il] = (bf16)rv.x;
        ldsT[(10 * 128 + o4 + 1) * 8 + il] = (bf16)rv.y;
        ldsT[(10 * 128 + o4 + 2) * 8 + il] = (bf16)rv.z;
        ldsT[(10 * 128 + o4 + 3) * 8 + il] = (bf16)rv.w;
        __syncthreads();
        if (tid < 128) {
            int o = tid;
            bf16* dst = bpk + (size_t)l * 128 * KTOT + (size_t)o * KTOT + chunk * 8;
            #pragma unroll
            for (int f = 0; f < 11; ++f) {
                bf16x8 val = *(bf16x8*)(ldsT + ((size_t)f * 128 + o) * 8);
                *(bf16x8*)(dst + f * 128) = val;
            }
        }
    }
}

// ================= k_layer v4 (R16-validated, unchanged): 1024 threads / 16 waves =================
__global__ __launch_bounds__(1024) void k_layer(const bf16* __restrict__ zin,
                                                float* __restrict__ h,
                                                const bf16* __restrict__ bpkL,
                                                const float* __restrict__ conv_b,
                                                const float* __restrict__ lng,
                                                const float* __restrict__ lnb,
                                                bf16* __restrict__ zout,
                                                float* __restrict__ tbuf,
                                                const int* __restrict__ deg,
                                                const int* __restrict__ csrs,
                                                const float* __restrict__ csrw,
                                                int l) {
    __shared__ bf16 As[16][ALD2];
    __shared__ float outs[2][16][128];
    int tid = threadIdx.x, lane = tid & 63, wv = tid >> 6;
    int r0 = blockIdx.x * 16;
    {
        int r = wv;
        int d = r0 + r;
        float acc[10][2];
        #pragma unroll
        for (int f = 0; f < 10; ++f) { acc[f][0] = 0.f; acc[f][1] = 0.f; }
        int dg = 0;
        if (d < NND) { dg = deg[d]; if (dg > CSTR) dg = CSTR; }
        for (int k = 0; k < dg; ++k) {
            int idx = d * CSTR + k;
            int s = csrs[idx];
            bf16x2 zz = *(const bf16x2*)(zin + (size_t)s * NH + 2 * lane);
            float z0 = (float)zz[0], z1 = (float)zz[1];
            const float* ww = csrw + (size_t)idx * 10;
            #pragma unroll
            for (int f = 0; f < 10; ++f) {
                float wf = ww[f];
                acc[f][0] += wf * z0;
                acc[f][1] += wf * z1;
            }
        }
        #pragma unroll
        for (int f = 0; f < 10; ++f) {
            bf16x2 av; av[0] = (bf16)acc[f][0]; av[1] = (bf16)acc[f][1];
            *(bf16x2*)(&As[r][f * 128 + 2 * lane]) = av;
        }
        bf16x2 zr = *(const bf16x2*)(zin + (size_t)d * NH + 2 * lane);
        *(bf16x2*)(&As[r][1280 + 2 * lane]) = zr;
    }
    __syncthreads();
    {
        int rA = lane & 15, q = lane >> 4, q8 = q * 8;
        int ct = wv >> 1, kh = wv & 1;
        const bf16* Af = &As[rA][0];
        const bf16* B0 = bpkL + (size_t)(ct * 16 + rA) * KTOT;
        f32x4 aA = {0.f, 0.f, 0.f, 0.f};
        int ks0 = kh * 22;
        #pragma unroll 2
        for (int ks = 0; ks < 22; ++ks) {
            int kb = (ks0 + ks) * 32 + q8;
            bf16x8 av = *(const bf16x8*)(Af + kb);
            bf16x8 b0 = *(const bf16x8*)(B0 + kb);
            aA = __builtin_amdgcn_mfma_f32_16x16x32_bf16(av, b0, aA, 0, 0, 0);
        }
        #pragma unroll
        for (int reg = 0; reg < 4; ++reg)
            outs[kh][q * 4 + reg][ct * 16 + rA] = aA[reg];
    }
    __syncthreads();
    {
        int r = wv;
        int d = r0 + r;
        if (d >= NND) {
            if (l < NLAY - 1) {
                zout[d * NH + lane] = (bf16)0.f;
                zout[d * NH + lane + 64] = (bf16)0.f;
            }
        } else {
            float v0 = (outs[0][r][lane] + outs[1][r][lane]) + conv_b[l * NH + lane];
            float v1 = (outs[0][r][lane + 64] + outs[1][r][lane + 64]) + conv_b[l * NH + lane + 64];
            if (l > 0) {
                v0 += h[d * NH + lane];
                v1 += h[d * NH + lane + 64];
            }
            if (l < NLAY - 1) {
                h[d * NH + lane] = v0;
                h[d * NH + lane + 64] = v1;
            }
            float m = wred(v0 + v1) * (1.f / NH);
            float d0 = v0 - m, d1 = v1 - m;
            float var = wred(d0 * d0 + d1 * d1) * (1.f / NH);
            float rs = rsqrtf(var + 1e-5f);
            if (l < NLAY - 1) {
                int ln = l + 1;
                zout[d * NH + lane] = (bf16)geluf(d0 * rs * lng[ln * NH + lane] + lnb[ln * NH + lane]);
                zout[d * NH + lane + 64] = (bf16)geluf(d1 * rs * lng[ln * NH + lane + 64] + lnb[ln * NH + lane + 64]);
            } else {
                tbuf[(size_t)d * DD + lane] = geluf(d0 * rs * lng[lane] + lnb[lane]);
                tbuf[(size_t)d * DD + lane + 64] = geluf(d1 * rs * lng[lane + 64] + lnb[lane + 64]);
            }
        }
    }
    if (l == NLAY - 1) {
        for (int idx = tid; idx < 16 * PCD; idx += 1024) {
            int r = idx >> 5, pc = idx & 31;
            int d = r0 + r;
            if (d < NND) {
                int qq = d % LSEQ;
                float twoi = (float)(pc & ~1);
                float ang = (float)qq * expf(-twoi * 0.28782313662425572f);
                tbuf[(size_t)d * DD + NH + pc] = (pc & 1) ? cosf(ang) : sinf(ang);
            }
        }
    }
}

// ================= generic MFMA GEMM (R8-validated; qkv of layer 0) =================
__global__ __launch_bounds__(256) void k_gmm(const float* __restrict__ A,
                                             const bf16* __restrict__ bp,
                                             const float* __restrict__ biasP,
                                             float* __restrict__ C,
                                             int ksteps, int K, int PW, int act) {
    int lane = threadIdx.x & 63, wv = threadIdx.x >> 6;
    int m0 = blockIdx.y * 64 + wv * 16;
    int ct = blockIdx.x;
    int r = lane & 15, q = lane >> 4, q8 = q * 8;
    const float* Arow = A + (size_t)(m0 + r) * K;
    const bf16* Bb = bp + ((size_t)ct * 64 + r) * K;
    f32x4 a0 = {0.f,0.f,0.f,0.f}, a1 = a0, a2 = a0, a3 = a0;
    for (int ks = 0; ks < ksteps; ++ks) {
        int kb = ks * 32 + q8;
        float4 f0 = *(const float4*)(Arow + kb);
        float4 f1 = *(const float4*)(Arow + kb + 4);
        bf16x8 av;
        av[0] = (bf16)f0.x; av[1] = (bf16)f0.y; av[2] = (bf16)f0.z; av[3] = (bf16)f0.w;
        av[4] = (bf16)f1.x; av[5] = (bf16)f1.y; av[6] = (bf16)f1.z; av[7] = (bf16)f1.w;
        bf16x8 b0 = *(const bf16x8*)(Bb + 0 * 16 * K + kb);
        bf16x8 b1 = *(const bf16x8*)(Bb + 1 * 16 * K + kb);
        bf16x8 b2 = *(const bf16x8*)(Bb + 2 * 16 * K + kb);
        bf16x8 b3 = *(const bf16x8*)(Bb + 3 * 16 * K + kb);
        a0 = __builtin_amdgcn_mfma_f32_16x16x32_bf16(av, b0, a0, 0, 0, 0);
        a1 = __builtin_amdgcn_mfma_f32_16x16x32_bf16(av, b1, a1, 0, 0, 0);
        a2 = __builtin_amdgcn_mfma_f32_16x16x32_bf16(av, b2, a2, 0, 0, 0);
        a3 = __builtin_amdgcn_mfma_f32_16x16x32_bf16(av, b3, a3, 0, 0, 0);
    }
    int cb = ct * 64;
    #pragma unroll
    for (int reg = 0; reg < 4; ++reg) {
        float* Crow = C + (size_t)(m0 + q * 4 + reg) * PW + cb;
        float v0 = a0[reg] + biasP[cb + 0 * 16 + r];
        float v1 = a1[reg] + biasP[cb + 1 * 16 + r];
        float v2 = a2[reg] + biasP[cb + 2 * 16 + r];
        float v3 = a3[reg] + biasP[cb + 3 * 16 + r];
        if (act) { v0 = fmaxf(v0, 0.f); v1 = fmaxf(v1, 0.f); v2 = fmaxf(v2, 0.f); v3 = fmaxf(v3, 0.f); }
        Crow[0 * 16 + r] = v0;
        Crow[1 * 16 + r] = v1;
        Crow[2 * 16 + r] = v2;
        Crow[3 * 16 + r] = v3;
    }
}

// ================= k_pln v3: 1024 threads / 16 waves =================
// Phase 1: 12 waves x one 16-col tile (single chain); Phase 2: 16 waves x 1 row;
// Phase 3 tail: 1 = ffn1 (16 tiles, 1/wave), 2 = qkv (32 tiles, 2/wave)
__global__ __launch_bounds__(1024) void k_pln(const float* __restrict__ A,
                                              const bf16* __restrict__ bp,
                                              const float* __restrict__ biasP,
                                              int ksteps, int K,
                                              float* __restrict__ t,
                                              const float* __restrict__ g,
                                              const float* __restrict__ bvec,
                                              int tail,
                                              const bf16* __restrict__ tbp,
                                              const float* __restrict__ tbias_,
                                              float* __restrict__ tout,
                                              const float* __restrict__ lw,
                                              const float* __restrict__ lb,
                                              float* __restrict__ outp) {
    __shared__ float outs[16][PRJP];
    __shared__ bf16 Als[16][176];
    int tid = threadIdx.x, lane = tid & 63, wv = tid >> 6;   // wv in [0,16)
    int m0 = blockIdx.x * 16;
    // ---- phase 1: delta GEMM, waves 0-11 each own one 16-col tile ----
    if (wv < 12) {
        int r = lane & 15, q = lane >> 4, q8 = q * 8;
        const float* Arow = A + (size_t)(m0 + r) * K;
        int cb = wv * 16;
        const bf16* B0 = bp + ((size_t)(cb + r) * K);
        f32x4 a0 = {0.f,0.f,0.f,0.f};
        for (int ks = 0; ks < ksteps; ++ks) {
            int kb = ks * 32 + q8;
            float4 f0 = *(const float4*)(Arow + kb);
            float4 f1 = *(const float4*)(Arow + kb + 4);
            bf16x8 av;
            av[0] = (bf16)f0.x; av[1] = (bf16)f0.y; av[2] = (bf16)f0.z; av[3] = (bf16)f0.w;
            av[4] = (bf16)f1.x; av[5] = (bf16)f1.y; av[6] = (bf16)f1.z; av[7] = (bf16)f1.w;
            bf16x8 b0 = *(const bf16x8*)(B0 + kb);
            a0 = __builtin_amdgcn_mfma_f32_16x16x32_bf16(av, b0, a0, 0, 0, 0);
        }
        #pragma unroll
        for (int reg = 0; reg < 4; ++reg)
            outs[q * 4 + reg][cb + r] = a0[reg] + biasP[cb + r];
    }
    __syncthreads();
    // ---- phase 2: residual + LN, 16 waves x 1 row ----
    {
        int r = wv;
        int d = m0 + r;
        if (d < NND) {
            int c0 = lane, c1 = lane + 64, c2 = lane + 128;
            float v0 = outs[r][c0] + t[(size_t)d * DD + c0];
            float v1 = outs[r][c1] + t[(size_t)d * DD + c1];
            float v2 = (lane < 32) ? (outs[r][c2] + t[(size_t)d * DD + c2]) : 0.f;
            float m = wred(v0 + v1 + v2) * (1.f / DD);
            float d0 = v0 - m, d1 = v1 - m, d2 = (lane < 32) ? (v2 - m) : 0.f;
            float var = wred(d0 * d0 + d1 * d1 + d2 * d2) * (1.f / DD);
            float rs = rsqrtf(var + 1e-5f);
            float n0 = d0 * rs * g[c0] + bvec[c0];
            float n1 = d1 * rs * g[c1] + bvec[c1];
            float n2 = (lane < 32) ? (d2 * rs * g[c2] + bvec[c2]) : 0.f;
            t[(size_t)d * DD + c0] = n0;
            t[(size_t)d * DD + c1] = n1;
            if (lane < 32) t[(size_t)d * DD + c2] = n2;
            Als[r][c0] = (bf16)n0;
            Als[r][c1] = (bf16)n1;
            if (lane < 32) Als[r][c2] = (bf16)n2;
            if (tail == 0 && outp) {
                #pragma unroll
                for (int cls = 0; cls < NCLS; ++cls) {
                    float part = n0 * lw[c0 * NCLS + cls] + n1 * lw[c1 * NCLS + cls]
                               + ((lane < 32) ? n2 * lw[c2 * NCLS + cls] : 0.f);
                    float tot = wred(part);
                    if (lane == 0) outp[d * NCLS + cls] = tot + lb[cls];
                }
            }
        }
    }
    if (!tail) return;
    __syncthreads();
    // ---- phase 3: tail GEMM from LDS A-tile, 16-col tiles across 16 waves ----
    {
        int PW = (tail == 1) ? FFD : QKVP;
        int ntile = (tail == 1) ? 1 : 2;      // tiles per wave (16 cols each)
        int rA = lane & 15, q = lane >> 4, q8 = q * 8;
        for (int ctl = 0; ctl < ntile; ++ctl) {
            int cb = (wv * ntile + ctl) * 16;
            const bf16* Bb = tbp + ((size_t)cb + rA) * DD;
            f32x4 a0 = {0.f,0.f,0.f,0.f};
            #pragma unroll
            for (int ks = 0; ks < 5; ++ks) {
                int kb = ks * 32 + q8;
                bf16x8 av = *(const bf16x8*)(&Als[rA][0] + kb);
                bf16x8 b0 = *(const bf16x8*)(Bb + kb);
                a0 = __builtin_amdgcn_mfma_f32_16x16x32_bf16(av, b0, a0, 0, 0, 0);
            }
            #pragma unroll
            for (int reg = 0; reg < 4; ++reg) {
                float* Crow = tout + (size_t)(m0 + q * 4 + reg) * PW + cb;
                float v0 = a0[reg] + tbias_[cb + rA];
                if (tail == 1) v0 = fmaxf(v0, 0.f);
                Crow[rA] = v0;
            }
        }
    }
}

// ================= attention (R3-validated), qkv row stride QKVP =================
#define UPD4(ac, V) { ac.x = ac.x * corr + p * V.x; ac.y = ac.y * corr + p * V.y; \
                      ac.z = ac.z * corr + p * V.z; ac.w = ac.w * corr + p * V.w; }
__global__ __launch_bounds__(64) void k_attn(const float* __restrict__ qkv,
                                             float* __restrict__ aout) {
    __shared__ float4 Ks4[LSEQ * 5], Vs4[LSEQ * 5];
    int bh = blockIdx.x;
    int b = bh >> 3, hh = bh & 7;
    int tid = threadIdx.x;
    for (int i = tid; i < LSEQ * 5; i += 64) {
        int kq = i / 5, c4 = i - kq * 5;
        const float* rowp = qkv + (size_t)(b * LSEQ + kq) * QKVP + hh * HDD;
        Ks4[i] = ((const float4*)(rowp + DD))[c4];
        Vs4[i] = ((const float4*)(rowp + 2 * DD))[c4];
    }
    __syncthreads();
    int q = blockIdx.y * 64 + tid;
    if (q >= LSEQ) return;
    const float4* qp = (const float4*)(qkv + (size_t)(b * LSEQ + q) * QKVP + hh * HDD);
    float4 q0 = qp[0], q1 = qp[1], q2 = qp[2], q3 = qp[3], q4 = qp[4];
    const float scale = 0.22360679774997896f;
    float mx = -3.0e38f, sum = 0.f;
    float4 z = {0.f, 0.f, 0.f, 0.f};
    float4 ac0 = z, ac1 = z, ac2 = z, ac3 = z, ac4 = z;
    for (int k = 0; k < LSEQ; ++k) {
        const float4* kp = Ks4 + k * 5;
        float4 K0 = kp[0], K1 = kp[1], K2 = kp[2], K3 = kp[3], K4 = kp[4];
        float a0 = q0.x * K0.x + q0.y * K0.y + q0.z * K0.z + q0.w * K0.w;
        float a1 = q1.x * K1.x + q1.y * K1.y + q1.z * K1.z + q1.w * K1.w;
        float a2 = q2.x * K2.x + q2.y * K2.y + q2.z * K2.z + q2.w * K2.w;
        float a3 = q3.x * K3.x + q3.y * K3.y + q3.z * K3.z + q3.w * K3.w;
        float a4 = q4.x * K4.x + q4.y * K4.y + q4.z * K4.z + q4.w * K4.w;
        float s = (((a0 + a1) + (a2 + a3)) + a4) * scale;
        float mn = fmaxf(mx, s);
        float corr = __expf(mx - mn);
        float p = __expf(s - mn);
        mx = mn;
        sum = sum * corr + p;
        const float4* vp = Vs4 + k * 5;
        float4 V0 = vp[0], V1 = vp[1], V2 = vp[2], V3 = vp[3], V4 = vp[4];
        UPD4(ac0, V0); UPD4(ac1, V1); UPD4(ac2, V2); UPD4(ac3, V3); UPD4(ac4, V4);
    }
    float inv = 1.f / sum;
    float4* op = (float4*)(aout + (size_t)(b * LSEQ + q) * DD + hh * HDD);
    float4 o0 = {ac0.x * inv, ac0.y * inv, ac0.z * inv, ac0.w * inv};
    float4 o1 = {ac1.x * inv, ac1.y * inv, ac1.z * inv, ac1.w * inv};
    float4 o2 = {ac2.x * inv, ac2.y * inv, ac2.z * inv, ac2.w * inv};
    float4 o3 = {ac3.x * inv, ac3.y * inv, ac3.z * inv, ac3.w * inv};
    float4 o4 = {ac4.x * inv, ac4.y * inv, ac4.z * inv, ac4.w * inv};
    op[0] = o0; op[1] = o1; op[2] = o2; op[3] = o3; op[4] = o4;
}

extern "C" void kernel_launch(void* const* d_in, const int* in_sizes, int n_in,
                              void* d_out, int out_size, void* d_ws, size_t ws_size,
                              hipStream_t stream) {
    (void)in_sizes; (void)n_in; (void)out_size; (void)ws_size;
    const float* x      = (const float*)d_in[0];
    const float* eattr  = (const float*)d_in[1];
    const float* cheb_w = (const float*)d_in[2];
    const float* cheb_b = (const float*)d_in[3];
    const float* ee_w   = (const float*)d_in[4];
    const float* ee_b   = (const float*)d_in[5];
    const float* mlp_w1 = (const float*)d_in[6];
    const float* mlp_b1 = (const float*)d_in[7];
    const float* mlp_w2 = (const float*)d_in[8];
    const float* mlp_b2 = (const float*)d_in[9];
    const float* root_w = (const float*)d_in[10];
    const float* conv_b = (const float*)d_in[11];
    const float* ln_g   = (const float*)d_in[12];
    const float* ln_b   = (const float*)d_in[13];
    const float* ain_w  = (const float*)d_in[14];
    const float* ain_b  = (const float*)d_in[15];
    const float* aow    = (const float*)d_in[16];
    const float* aob    = (const float*)d_in[17];
    const float* ffw1   = (const float*)d_in[18];
    const float* ffb1   = (const float*)d_in[19];
    const float* ffw2   = (const float*)d_in[20];
    const float* ffb2   = (const float*)d_in[21];
    const float* t1g    = (const float*)d_in[22];
    const float* t1b    = (const float*)d_in[23];
    const float* t2g    = (const float*)d_in[24];
    const float* t2b    = (const float*)d_in[25];
    const float* lin_w  = (const float*)d_in[26];
    const float* lin_b  = (const float*)d_in[27];
    const int* ei       = (const int*)d_in[29];

    char* w = (char*)d_ws;
    size_t off = 0;
    auto alloc = [&](size_t bytes) -> void* {
        void* p = w + off;
        off += (bytes + 255) & ~(size_t)255;
        return p;
    };
    bf16*  bpk   = (bf16*)alloc((size_t)NLAY * 128 * KTOT * 2);
    float* h     = (float*)alloc((size_t)NND * NH * 4);
    bf16*  zA    = (bf16*)alloc((size_t)NPAD * NH * 2);
    bf16*  zB    = (bf16*)alloc((size_t)NPAD * NH * 2);
    float* tbuf  = (float*)alloc((size_t)NPAD * DD * 4);
    float* qkvC  = (float*)alloc((size_t)NPAD * QKVP * 4);
    float* abuf  = (float*)alloc((size_t)NPAD * DD * 4);
    float* f1    = (float*)alloc((size_t)NPAD * FFD * 4);
    int*   deg   = (int*)alloc((size_t)NND * 4);
    int*   csrs  = (int*)alloc((size_t)NND * CSTR * 4);
    float* csrw  = (float*)alloc((size_t)NND * CSTR * 10 * 4);
    bf16*  bqkv  = (bf16*)alloc((size_t)TLAY * QKVP * DD * 2);
    bf16*  bproj = (bf16*)alloc((size_t)TLAY * PRJP * DD * 2);
    bf16*  bff1  = (bf16*)alloc((size_t)TLAY * FFD * DD * 2);
    bf16*  bff2  = (bf16*)alloc((size_t)TLAY * PRJP * FFD * 2);
    float* tbias = (float*)alloc((size_t)TLAY * 1152 * 4);

    k_setup<<<SB_TOT, 256, 0, stream>>>(x, cheb_w, cheb_b, zA, zB,
                                        eattr, ee_w, ee_b, mlp_w1, mlp_b1,
                                        mlp_w2, mlp_b2, root_w, bpk,
                                        ei, deg, csrs, csrw,
                                        ain_w, aow, ffw1, ffw2,
                                        ain_b, aob, ffb1, ffb2,
                                        bqkv, bproj, bff1, bff2, tbias);

    // --- 10 NNConv layers: ONE dispatch each, 1024-thread blocks ---
    bf16* zcur = zA;
    bf16* znxt = zB;
    for (int l = 0; l < NLAY; ++l) {
        k_layer<<<NPAD / 16, 1024, 0, stream>>>(zcur, h, bpk + (size_t)l * 128 * KTOT,
                                                conv_b, ln_g, ln_b, znxt, tbuf,
                                                deg, csrs, csrw, l);
        bf16* tmp = zcur; zcur = znxt; znxt = tmp;
    }

    // --- transformer encoder: qkv0, then {attn, plnA(+ffn1), plnB(+qkv_next | final)} ---
    k_gmm<<<dim3(QKVP / 64, 14), 256, 0, stream>>>(tbuf, bqkv, tbias, qkvC, 5, DD, QKVP, 0);
    for (int tl = 0; tl < TLAY; ++tl) {
        const float* bb = tbias + (size_t)tl * 1152;
        k_attn<<<dim3(BSZ * THD, 2), 64, 0, stream>>>(qkvC, abuf);
        k_pln<<<NPAD / 16, 1024, 0, stream>>>(abuf, bproj + (size_t)tl * PRJP * DD, bb + 512,
                                              5, DD, tbuf,
                                              t1g + (size_t)tl * DD, t1b + (size_t)tl * DD,
                                              1, bff1 + (size_t)tl * FFD * DD, bb + 704, f1,
                                              nullptr, nullptr, nullptr);
        int last = (tl == TLAY - 1);
        k_pln<<<NPAD / 16, 1024, 0, stream>>>(f1, bff2 + (size_t)tl * PRJP * FFD, bb + 960,
                                              8, FFD, tbuf,
                                              t2g + (size_t)tl * DD, t2b + (size_t)tl * DD,
                                              last ? 0 : 2,
                                              last ? nullptr : bqkv + (size_t)(tl + 1) * QKVP * DD,
                                              last ? nullptr : tbias + (size_t)(tl + 1) * 1152,
                                              last ? nullptr : qkvC,
                                              last ? lin_w : nullptr,
                                              last ? lin_b : nullptr,
                                              last ? (float*)d_out : nullptr);
    }
}

// Round 18
// 442.870 us; speedup vs baseline: 1.0153x; 1.0153x over previous
//
#include <hip/hip_runtime.h>
#include <hip/hip_bf16.h>
#include <math.h>

// ---------------- problem constants ----------------
#define BSZ   8
#define LSEQ  107
#define NNF   17
#define NEF   9
#define NH    128
#define EHD   32
#define H3D   32
#define NLAY  10
#define PCD   32
#define TLAY  3
#define THD   8
#define FFD   256
#define NCLS  3
#define DD    160          // NH + PC
#define HDD   20           // D / TH
#define NND   856          // nodes
#define NPAD  896          // padded to 14*64
#define NE    2896         // edges
#define CSTR  32           // CSR bucket stride (max in-degree bound)
#define QKVP  512          // padded qkv width
#define PRJP  192          // padded proj/ffn2 width
#define KTOT  1408         // 10*128 (rank-10 A) + 128 (root)
#define ALD2  1416         // padded LDS k-stride (bf16)

// k_setup block partition
#define SB_CHEB 428
#define SB_PAD  (SB_CHEB)          // 428: zero zA/zB pad rows
#define SB_CSR1 (SB_PAD + 1)       // 429: single-block packed-CSR build (src + weights)
#define SB_TPK  (SB_CSR1 + 1)      // 430: transformer weight pack (R9-validated)
#define NTPK    171
#define SB_BIAS (SB_TPK + NTPK)    // 601
#define SB_WT   (SB_BIAS + 1)      // 602: W-tilde pack v2 (R11-validated)
#define NWT     160                // 10 layers x 16 io-chunks
#define SB_TOT  (SB_WT + NWT)      // 762

typedef __bf16 bf16;
typedef __bf16 bf16x2 __attribute__((ext_vector_type(2)));
typedef __bf16 bf16x8 __attribute__((ext_vector_type(8)));
typedef float  f32x4  __attribute__((ext_vector_type(4)));

__device__ __forceinline__ float geluf(float z) {
    return 0.5f * z * (1.0f + erff(z * 0.70710678118654752f));
}
__device__ __forceinline__ float wred(float v) {
    #pragma unroll
    for (int o = 32; o; o >>= 1) v += __shfl_xor(v, o, 64);
    return v;
}
__device__ __forceinline__ float dinv_path(int n) {
    return (n == 0 || n == LSEQ - 1) ? 1.0f : 0.70710678118654752f;
}

// ================= k_setup (R13/R14-validated, unchanged) =================
__global__ __launch_bounds__(256) void k_setup(
        const float* __restrict__ x, const float* __restrict__ cw,
        const float* __restrict__ cb, bf16* __restrict__ zA, bf16* __restrict__ zB,
        const float* __restrict__ eattr, const float* __restrict__ eew,
        const float* __restrict__ eeb, const float* __restrict__ w1,
        const float* __restrict__ b1,
        const float* __restrict__ w2, const float* __restrict__ b2,
        const float* __restrict__ rootw, bf16* __restrict__ bpk,
        const int* __restrict__ ei, int* __restrict__ deg,
        int* __restrict__ csrs, float* __restrict__ csrw,
        const float* __restrict__ ain_w, const float* __restrict__ aow,
        const float* __restrict__ ffw1, const float* __restrict__ ffw2,
        const float* __restrict__ ain_b, const float* __restrict__ aob,
        const float* __restrict__ ffb1, const float* __restrict__ ffb2,
        bf16* __restrict__ bqkv, bf16* __restrict__ bproj,
        bf16* __restrict__ bff1, bf16* __restrict__ bff2,
        float* __restrict__ tb_bias) {
    __shared__ __align__(16) char sm[24576];
    int blk = blockIdx.x, tid = threadIdx.x;
    if (blk < SB_CHEB) {
        float (*xs)[5][NNF] = (float (*)[5][NNF])sm;
        int s = tid >> 7, o = tid & 127;
        int n = blk * 2 + s;
        int g = n / LSEQ, i = n - g * LSEQ;
        if (o < 5 * NNF) {
            int k = o / NNF, f = o - k * NNF;
            int p = i - 2 + k; p = p < 0 ? 0 : (p > LSEQ - 1 ? LSEQ - 1 : p);
            xs[s][k][f] = x[(g * LSEQ + p) * NNF + f];
        }
        __syncthreads();
        float di  = dinv_path(i);
        float dm1 = dinv_path(i - 1 < 0 ? 0 : i - 1);
        float dp1 = dinv_path(i + 1 > LSEQ - 1 ? LSEQ - 1 : i + 1);
        float dm2 = dinv_path(i - 2 < 0 ? 0 : i - 2);
        float dp2 = dinv_path(i + 2 > LSEQ - 1 ? LSEQ - 1 : i + 2);
        float wmc = (i > 0)        ? -(dm1 * di) : 0.f;
        float wpc = (i < LSEQ - 1) ? -(dp1 * di) : 0.f;
        float wmm = (i - 1 > 0)        ? -(dm2 * dm1) : 0.f;
        float wpm = -(di * dm1);
        float wmp = -(di * dp1);
        float wpp = (i + 1 < LSEQ - 1) ? -(dp2 * dp1) : 0.f;
        float acc = cb[o];
        #pragma unroll
        for (int f = 0; f < NNF; ++f) {
            float xm2 = xs[s][0][f], xm1 = xs[s][1][f], x0 = xs[s][2][f],
                  xp1 = xs[s][3][f], xp2 = xs[s][4][f];
            float t1c = wmc * xm1 + wpc * xp1;
            float t1m = wmm * xm2 + wpm * x0;
            float t1p = wmp * x0 + wpp * xp2;
            float t2 = 2.f * (wmc * t1m + wpc * t1p) - x0;
            acc += x0 * cw[f * NH + o] + t1c * cw[(NNF + f) * NH + o]
                 + t2 * cw[(2 * NNF + f) * NH + o];
        }
        zA[n * NH + o] = (bf16)acc;
    } else if (blk == SB_PAD) {
        for (int i = tid; i < (NPAD - NND) * NH; i += 256) {
            zA[NND * NH + i] = (bf16)0.f;
            zB[NND * NH + i] = (bf16)0.f;
        }
    } else if (blk == SB_CSR1) {
        int* ldeg = (int*)sm;
        for (int i = tid; i < NND; i += 256) ldeg[i] = 0;
        __syncthreads();
        for (int e = tid; e < NE; e += 256) {
            int d = ei[NE + e];
            int slot = atomicAdd(&ldeg[d], 1);
            if (slot < CSTR) {
                int idx = d * CSTR + slot;
                csrs[idx] = ei[e];
                float* wp = csrw + (size_t)idx * 10;
                #pragma unroll
                for (int f = 0; f < NEF; ++f) wp[f] = eattr[e * NEF + f];
                wp[9] = 1.0f;
            }
        }
        __syncthreads();
        for (int i = tid; i < NND; i += 256) deg[i] = ldeg[i];
    } else if (blk < SB_BIAS) {
        bf16 (*tt)[65] = (bf16 (*)[65])sm;
        int v = blk - SB_TPK;
        int tl = v / 57, t = v % 57;
        const float* src; bf16* dst; int Kd, srcN, ct, kt;
        if (t < 24)      { ct = t & 7;  kt = t >> 3;          src = ain_w + (size_t)tl * DD * 3 * DD; srcN = 3 * DD; Kd = DD;  dst = bqkv  + (size_t)tl * QKVP * DD; }
        else if (t < 33) { int u = t - 24; ct = u % 3; kt = u / 3; src = aow + (size_t)tl * DD * DD;  srcN = DD;     Kd = DD;  dst = bproj + (size_t)tl * PRJP * DD; }
        else if (t < 45) { int u = t - 33; ct = u % 4; kt = u / 4; src = ffw1 + (size_t)tl * DD * FFD; srcN = FFD;   Kd = DD;  dst = bff1  + (size_t)tl * FFD * DD; }
        else             { int u = t - 45; ct = u % 3; kt = u / 3; src = ffw2 + (size_t)tl * FFD * DD; srcN = DD;    Kd = FFD; dst = bff2  + (size_t)tl * PRJP * FFD; }
        int cc = tid & 63, rr = tid >> 6;
        #pragma unroll
        for (int rep = 0; rep < 16; ++rep) {
            int kl = rep * 4 + rr;
            int k = kt * 64 + kl;
            int col = ct * 64 + cc;
            float val = (k < Kd && col < srcN) ? src[(size_t)k * srcN + col] : 0.f;
            tt[kl][cc] = (bf16)val;
        }
        __syncthreads();
        int k = kt * 64 + cc;
        if (k < Kd) {
            #pragma unroll
            for (int rep = 0; rep < 16; ++rep) {
                int c = rep * 4 + rr;
                dst[(size_t)(ct * 64 + c) * Kd + k] = tt[cc][c];
            }
        }
    } else if (blk == SB_BIAS) {
        for (int i = tid; i < 3 * 1152; i += 256) {
            int tl = i / 1152, r = i % 1152;
            float val;
            if (r < 512)      { val = (r < 480) ? ain_b[tl * 480 + r] : 0.f; }
            else if (r < 704) { int c = r - 512; val = (c < 160) ? aob[tl * 160 + c] : 0.f; }
            else if (r < 960) { int c = r - 704; val = ffb1[tl * 256 + c]; }
            else              { int c = r - 960; val = (c < 160) ? ffb2[tl * 160 + c] : 0.f; }
            tb_bias[i] = val;
        }
    } else {
        float* gw  = (float*)sm;               // [10][32]
        bf16* ldsT = (bf16*)(sm + 2048);       // [11][128][8]
        int v = blk - SB_WT;
        int l = v >> 4, chunk = v & 15;
        int io0 = chunk * 1024;
        for (int e = tid; e < 320; e += 256) {
            int f = e >> 5, j = e & 31;
            float acc;
            if (f < 9) {
                acc = 0.f;
                for (int m = 0; m < EHD; ++m)
                    acc += eew[f * EHD + m] * w1[(size_t)l * EHD * H3D + m * H3D + j];
            } else {
                acc = b1[l * H3D + j];
                for (int m = 0; m < EHD; ++m)
                    acc += eeb[m] * w1[(size_t)l * EHD * H3D + m * H3D + j];
            }
            gw[e] = acc;
        }
        __syncthreads();
        int io = io0 + tid * 4;
        const float* w2l = w2 + (size_t)l * 524288;
        float acc[10][4];
        float4 b2v = *(const float4*)(b2 + (size_t)l * 16384 + io);
        #pragma unroll
        for (int f = 0; f < 9; ++f) { acc[f][0] = 0.f; acc[f][1] = 0.f; acc[f][2] = 0.f; acc[f][3] = 0.f; }
        acc[9][0] = b2v.x; acc[9][1] = b2v.y; acc[9][2] = b2v.z; acc[9][3] = b2v.w;
        for (int j = 0; j < H3D; ++j) {
            float4 wv4 = *(const float4*)(w2l + (size_t)j * 16384 + io);
            #pragma unroll
            for (int f = 0; f < 10; ++f) {
                float gf = gw[f * 32 + j];
                acc[f][0] += gf * wv4.x; acc[f][1] += gf * wv4.y;
                acc[f][2] += gf * wv4.z; acc[f][3] += gf * wv4.w;
            }
        }
        int o4 = (tid & 31) * 4, il = tid >> 5;
        #pragma unroll
        for (int f = 0; f < 10; ++f)
            #pragma unroll
            for (int k = 0; k < 4; ++k)
                ldsT[(f * 128 + o4 + k) * 8 + il] = (bf16)acc[f][k];
        float4 rv = *(const float4*)(rootw + (size_t)l * 16384 + io);
        ldsT[(10 * 128 + o4 + 0) * 8 + il] = (bf16)rv.x;
        ldsT[(10 * 128 + o4 + 1) * 8 + il] = (bf16)rv.y;
        ldsT[(10 * 128 + o4 + 2) * 8 + il] = (bf16)rv.z;
        ldsT[(10 * 128 + o4 + 3) * 8 + il] = (bf16)rv.w;
        __syncthreads();
        if (tid < 128) {
            int o = tid;
            bf16* dst = bpk + (size_t)l * 128 * KTOT + (size_t)o * KTOT + chunk * 8;
            #pragma unroll
            for (int f = 0; f < 11; ++f) {
                bf16x8 val = *(bf16x8*)(ldsT + ((size_t)f * 128 + o) * 8);
                *(bf16x8*)(dst + f * 128) = val;
            }
        }
    }
}

// ================= k_layer v4 (R16-validated): 1024 threads / 16 waves, K-split wave pairs =================
__global__ __launch_bounds__(1024) void k_layer(const bf16* __restrict__ zin,
                                                float* __restrict__ h,
                                                const bf16* __restrict__ bpkL,
                                                const float* __restrict__ conv_b,
                                                const float* __restrict__ lng,
                                                const float* __restrict__ lnb,
                                                bf16* __restrict__ zout,
                                                float* __restrict__ tbuf,
                                                const int* __restrict__ deg,
                                                const int* __restrict__ csrs,
                                                const float* __restrict__ csrw,
                                                int l) {
    __shared__ bf16 As[16][ALD2];
    __shared__ float outs[2][16][128];
    int tid = threadIdx.x, lane = tid & 63, wv = tid >> 6;
    int r0 = blockIdx.x * 16;
    {
        int r = wv;
        int d = r0 + r;
        float acc[10][2];
        #pragma unroll
        for (int f = 0; f < 10; ++f) { acc[f][0] = 0.f; acc[f][1] = 0.f; }
        int dg = 0;
        if (d < NND) { dg = deg[d]; if (dg > CSTR) dg = CSTR; }
        for (int k = 0; k < dg; ++k) {
            int idx = d * CSTR + k;
            int s = csrs[idx];
            bf16x2 zz = *(const bf16x2*)(zin + (size_t)s * NH + 2 * lane);
            float z0 = (float)zz[0], z1 = (float)zz[1];
            const float* ww = csrw + (size_t)idx * 10;
            #pragma unroll
            for (int f = 0; f < 10; ++f) {
                float wf = ww[f];
                acc[f][0] += wf * z0;
                acc[f][1] += wf * z1;
            }
        }
        #pragma unroll
        for (int f = 0; f < 10; ++f) {
            bf16x2 av; av[0] = (bf16)acc[f][0]; av[1] = (bf16)acc[f][1];
            *(bf16x2*)(&As[r][f * 128 + 2 * lane]) = av;
        }
        bf16x2 zr = *(const bf16x2*)(zin + (size_t)d * NH + 2 * lane);
        *(bf16x2*)(&As[r][1280 + 2 * lane]) = zr;
    }
    __syncthreads();
    {
        int rA = lane & 15, q = lane >> 4, q8 = q * 8;
        int ct = wv >> 1, kh = wv & 1;
        const bf16* Af = &As[rA][0];
        const bf16* B0 = bpkL + (size_t)(ct * 16 + rA) * KTOT;
        f32x4 aA = {0.f, 0.f, 0.f, 0.f};
        int ks0 = kh * 22;
        #pragma unroll 2
        for (int ks = 0; ks < 22; ++ks) {
            int kb = (ks0 + ks) * 32 + q8;
            bf16x8 av = *(const bf16x8*)(Af + kb);
            bf16x8 b0 = *(const bf16x8*)(B0 + kb);
            aA = __builtin_amdgcn_mfma_f32_16x16x32_bf16(av, b0, aA, 0, 0, 0);
        }
        #pragma unroll
        for (int reg = 0; reg < 4; ++reg)
            outs[kh][q * 4 + reg][ct * 16 + rA] = aA[reg];
    }
    __syncthreads();
    {
        int r = wv;
        int d = r0 + r;
        if (d >= NND) {
            if (l < NLAY - 1) {
                zout[d * NH + lane] = (bf16)0.f;
                zout[d * NH + lane + 64] = (bf16)0.f;
            }
        } else {
            float v0 = (outs[0][r][lane] + outs[1][r][lane]) + conv_b[l * NH + lane];
            float v1 = (outs[0][r][lane + 64] + outs[1][r][lane + 64]) + conv_b[l * NH + lane + 64];
            if (l > 0) {
                v0 += h[d * NH + lane];
                v1 += h[d * NH + lane + 64];
            }
            if (l < NLAY - 1) {
                h[d * NH + lane] = v0;
                h[d * NH + lane + 64] = v1;
            }
            float m = wred(v0 + v1) * (1.f / NH);
            float d0 = v0 - m, d1 = v1 - m;
            float var = wred(d0 * d0 + d1 * d1) * (1.f / NH);
            float rs = rsqrtf(var + 1e-5f);
            if (l < NLAY - 1) {
                int ln = l + 1;
                zout[d * NH + lane] = (bf16)geluf(d0 * rs * lng[ln * NH + lane] + lnb[ln * NH + lane]);
                zout[d * NH + lane + 64] = (bf16)geluf(d1 * rs * lng[ln * NH + lane + 64] + lnb[ln * NH + lane + 64]);
            } else {
                tbuf[(size_t)d * DD + lane] = geluf(d0 * rs * lng[lane] + lnb[lane]);
                tbuf[(size_t)d * DD + lane + 64] = geluf(d1 * rs * lng[lane + 64] + lnb[lane + 64]);
            }
        }
    }
    if (l == NLAY - 1) {
        for (int idx = tid; idx < 16 * PCD; idx += 1024) {
            int r = idx >> 5, pc = idx & 31;
            int d = r0 + r;
            if (d < NND) {
                int qq = d % LSEQ;
                float twoi = (float)(pc & ~1);
                float ang = (float)qq * expf(-twoi * 0.28782313662425572f);
                tbuf[(size_t)d * DD + NH + pc] = (pc & 1) ? cosf(ang) : sinf(ang);
            }
        }
    }
}

// ================= generic MFMA GEMM (R8-validated; qkv of layer 0) =================
__global__ __launch_bounds__(256) void k_gmm(const float* __restrict__ A,
                                             const bf16* __restrict__ bp,
                                             const float* __restrict__ biasP,
                                             float* __restrict__ C,
                                             int ksteps, int K, int PW, int act) {
    int lane = threadIdx.x & 63, wv = threadIdx.x >> 6;
    int m0 = blockIdx.y * 64 + wv * 16;
    int ct = blockIdx.x;
    int r = lane & 15, q = lane >> 4, q8 = q * 8;
    const float* Arow = A + (size_t)(m0 + r) * K;
    const bf16* Bb = bp + ((size_t)ct * 64 + r) * K;
    f32x4 a0 = {0.f,0.f,0.f,0.f}, a1 = a0, a2 = a0, a3 = a0;
    for (int ks = 0; ks < ksteps; ++ks) {
        int kb = ks * 32 + q8;
        float4 f0 = *(const float4*)(Arow + kb);
        float4 f1 = *(const float4*)(Arow + kb + 4);
        bf16x8 av;
        av[0] = (bf16)f0.x; av[1] = (bf16)f0.y; av[2] = (bf16)f0.z; av[3] = (bf16)f0.w;
        av[4] = (bf16)f1.x; av[5] = (bf16)f1.y; av[6] = (bf16)f1.z; av[7] = (bf16)f1.w;
        bf16x8 b0 = *(const bf16x8*)(Bb + 0 * 16 * K + kb);
        bf16x8 b1 = *(const bf16x8*)(Bb + 1 * 16 * K + kb);
        bf16x8 b2 = *(const bf16x8*)(Bb + 2 * 16 * K + kb);
        bf16x8 b3 = *(const bf16x8*)(Bb + 3 * 16 * K + kb);
        a0 = __builtin_amdgcn_mfma_f32_16x16x32_bf16(av, b0, a0, 0, 0, 0);
        a1 = __builtin_amdgcn_mfma_f32_16x16x32_bf16(av, b1, a1, 0, 0, 0);
        a2 = __builtin_amdgcn_mfma_f32_16x16x32_bf16(av, b2, a2, 0, 0, 0);
        a3 = __builtin_amdgcn_mfma_f32_16x16x32_bf16(av, b3, a3, 0, 0, 0);
    }
    int cb = ct * 64;
    #pragma unroll
    for (int reg = 0; reg < 4; ++reg) {
        float* Crow = C + (size_t)(m0 + q * 4 + reg) * PW + cb;
        float v0 = a0[reg] + biasP[cb + 0 * 16 + r];
        float v1 = a1[reg] + biasP[cb + 1 * 16 + r];
        float v2 = a2[reg] + biasP[cb + 2 * 16 + r];
        float v3 = a3[reg] + biasP[cb + 3 * 16 + r];
        if (act) { v0 = fmaxf(v0, 0.f); v1 = fmaxf(v1, 0.f); v2 = fmaxf(v2, 0.f); v3 = fmaxf(v3, 0.f); }
        Crow[0 * 16 + r] = v0;
        Crow[1 * 16 + r] = v1;
        Crow[2 * 16 + r] = v2;
        Crow[3 * 16 + r] = v3;
    }
}

// ================= k_pln v2 (R15/R16-validated): 512 threads / 8 waves =================
__global__ __launch_bounds__(512) void k_pln(const float* __restrict__ A,
                                             const bf16* __restrict__ bp,
                                             const float* __restrict__ biasP,
                                             int ksteps, int K,
                                             float* __restrict__ t,
                                             const float* __restrict__ g,
                                             const float* __restrict__ bvec,
                                             int tail,
                                             const bf16* __restrict__ tbp,
                                             const float* __restrict__ tbias_,
                                             float* __restrict__ tout,
                                             const float* __restrict__ lw,
                                             const float* __restrict__ lb,
                                             float* __restrict__ outp) {
    __shared__ float outs[16][PRJP];
    __shared__ bf16 Als[16][176];
    int tid = threadIdx.x, lane = tid & 63, wv = tid >> 6;   // wv in [0,8)
    int m0 = blockIdx.x * 16;
    if (wv < 6) {
        int r = lane & 15, q = lane >> 4, q8 = q * 8;
        const float* Arow = A + (size_t)(m0 + r) * K;
        int cb0 = wv * 32;
        const bf16* B0 = bp + ((size_t)(cb0 + r) * K);
        const bf16* B1 = bp + ((size_t)(cb0 + 16 + r) * K);
        f32x4 a0 = {0.f,0.f,0.f,0.f}, a1 = a0;
        for (int ks = 0; ks < ksteps; ++ks) {
            int kb = ks * 32 + q8;
            float4 f0 = *(const float4*)(Arow + kb);
            float4 f1 = *(const float4*)(Arow + kb + 4);
            bf16x8 av;
            av[0] = (bf16)f0.x; av[1] = (bf16)f0.y; av[2] = (bf16)f0.z; av[3] = (bf16)f0.w;
            av[4] = (bf16)f1.x; av[5] = (bf16)f1.y; av[6] = (bf16)f1.z; av[7] = (bf16)f1.w;
            bf16x8 b0 = *(const bf16x8*)(B0 + kb);
            bf16x8 b1 = *(const bf16x8*)(B1 + kb);
            a0 = __builtin_amdgcn_mfma_f32_16x16x32_bf16(av, b0, a0, 0, 0, 0);
            a1 = __builtin_amdgcn_mfma_f32_16x16x32_bf16(av, b1, a1, 0, 0, 0);
        }
        #pragma unroll
        for (int reg = 0; reg < 4; ++reg) {
            int rw = q * 4 + reg;
            outs[rw][cb0 + r] = a0[reg] + biasP[cb0 + r];
            outs[rw][cb0 + 16 + r] = a1[reg] + biasP[cb0 + 16 + r];
        }
    }
    __syncthreads();
    for (int rr = 0; rr < 2; ++rr) {
        int r = wv * 2 + rr;
        int d = m0 + r;
        if (d >= NND) continue;
        int c0 = lane, c1 = lane + 64, c2 = lane + 128;
        float v0 = outs[r][c0] + t[(size_t)d * DD + c0];
        float v1 = outs[r][c1] + t[(size_t)d * DD + c1];
        float v2 = (lane < 32) ? (outs[r][c2] + t[(size_t)d * DD + c2]) : 0.f;
        float m = wred(v0 + v1 + v2) * (1.f / DD);
        float d0 = v0 - m, d1 = v1 - m, d2 = (lane < 32) ? (v2 - m) : 0.f;
        float var = wred(d0 * d0 + d1 * d1 + d2 * d2) * (1.f / DD);
        float rs = rsqrtf(var + 1e-5f);
        float n0 = d0 * rs * g[c0] + bvec[c0];
        float n1 = d1 * rs * g[c1] + bvec[c1];
        float n2 = (lane < 32) ? (d2 * rs * g[c2] + bvec[c2]) : 0.f;
        t[(size_t)d * DD + c0] = n0;
        t[(size_t)d * DD + c1] = n1;
        if (lane < 32) t[(size_t)d * DD + c2] = n2;
        Als[r][c0] = (bf16)n0;
        Als[r][c1] = (bf16)n1;
        if (lane < 32) Als[r][c2] = (bf16)n2;
        if (tail == 0 && outp) {
            #pragma unroll
            for (int cls = 0; cls < NCLS; ++cls) {
                float part = n0 * lw[c0 * NCLS + cls] + n1 * lw[c1 * NCLS + cls]
                           + ((lane < 32) ? n2 * lw[c2 * NCLS + cls] : 0.f);
                float tot = wred(part);
                if (lane == 0) outp[d * NCLS + cls] = tot + lb[cls];
            }
        }
    }
    if (!tail) return;
    __syncthreads();
    {
        int PW = (tail == 1) ? FFD : QKVP;
        int ntile = (tail == 1) ? 2 : 4;
        int rA = lane & 15, q = lane >> 4, q8 = q * 8;
        for (int ctl = 0; ctl < ntile; ++ctl) {
            int cb = (wv * ntile + ctl) * 16;
            const bf16* Bb = tbp + ((size_t)cb + rA) * DD;
            f32x4 a0 = {0.f,0.f,0.f,0.f};
            #pragma unroll
            for (int ks = 0; ks < 5; ++ks) {
                int kb = ks * 32 + q8;
                bf16x8 av = *(const bf16x8*)(&Als[rA][0] + kb);
                bf16x8 b0 = *(const bf16x8*)(Bb + kb);
                a0 = __builtin_amdgcn_mfma_f32_16x16x32_bf16(av, b0, a0, 0, 0, 0);
            }
            #pragma unroll
            for (int reg = 0; reg < 4; ++reg) {
                float* Crow = tout + (size_t)(m0 + q * 4 + reg) * PW + cb;
                float v0 = a0[reg] + tbias_[cb + rA];
                if (tail == 1) v0 = fmaxf(v0, 0.f);
                Crow[rA] = v0;
            }
        }
    }
}

// ================= attention (R3-validated), qkv row stride QKVP =================
#define UPD4(ac, V) { ac.x = ac.x * corr + p * V.x; ac.y = ac.y * corr + p * V.y; \
                      ac.z = ac.z * corr + p * V.z; ac.w = ac.w * corr + p * V.w; }
__global__ __launch_bounds__(64) void k_attn(const float* __restrict__ qkv,
                                             float* __restrict__ aout) {
    __shared__ float4 Ks4[LSEQ * 5], Vs4[LSEQ * 5];
    int bh = blockIdx.x;
    int b = bh >> 3, hh = bh & 7;
    int tid = threadIdx.x;
    for (int i = tid; i < LSEQ * 5; i += 64) {
        int kq = i / 5, c4 = i - kq * 5;
        const float* rowp = qkv + (size_t)(b * LSEQ + kq) * QKVP + hh * HDD;
        Ks4[i] = ((const float4*)(rowp + DD))[c4];
        Vs4[i] = ((const float4*)(rowp + 2 * DD))[c4];
    }
    __syncthreads();
    int q = blockIdx.y * 64 + tid;
    if (q >= LSEQ) return;
    const float4* qp = (const float4*)(qkv + (size_t)(b * LSEQ + q) * QKVP + hh * HDD);
    float4 q0 = qp[0], q1 = qp[1], q2 = qp[2], q3 = qp[3], q4 = qp[4];
    const float scale = 0.22360679774997896f;
    float mx = -3.0e38f, sum = 0.f;
    float4 z = {0.f, 0.f, 0.f, 0.f};
    float4 ac0 = z, ac1 = z, ac2 = z, ac3 = z, ac4 = z;
    for (int k = 0; k < LSEQ; ++k) {
        const float4* kp = Ks4 + k * 5;
        float4 K0 = kp[0], K1 = kp[1], K2 = kp[2], K3 = kp[3], K4 = kp[4];
        float a0 = q0.x * K0.x + q0.y * K0.y + q0.z * K0.z + q0.w * K0.w;
        float a1 = q1.x * K1.x + q1.y * K1.y + q1.z * K1.z + q1.w * K1.w;
        float a2 = q2.x * K2.x + q2.y * K2.y + q2.z * K2.z + q2.w * K2.w;
        float a3 = q3.x * K3.x + q3.y * K3.y + q3.z * K3.z + q3.w * K3.w;
        float a4 = q4.x * K4.x + q4.y * K4.y + q4.z * K4.z + q4.w * K4.w;
        float s = (((a0 + a1) + (a2 + a3)) + a4) * scale;
        float mn = fmaxf(mx, s);
        float corr = __expf(mx - mn);
        float p = __expf(s - mn);
        mx = mn;
        sum = sum * corr + p;
        const float4* vp = Vs4 + k * 5;
        float4 V0 = vp[0], V1 = vp[1], V2 = vp[2], V3 = vp[3], V4 = vp[4];
        UPD4(ac0, V0); UPD4(ac1, V1); UPD4(ac2, V2); UPD4(ac3, V3); UPD4(ac4, V4);
    }
    float inv = 1.f / sum;
    float4* op = (float4*)(aout + (size_t)(b * LSEQ + q) * DD + hh * HDD);
    float4 o0 = {ac0.x * inv, ac0.y * inv, ac0.z * inv, ac0.w * inv};
    float4 o1 = {ac1.x * inv, ac1.y * inv, ac1.z * inv, ac1.w * inv};
    float4 o2 = {ac2.x * inv, ac2.y * inv, ac2.z * inv, ac2.w * inv};
    float4 o3 = {ac3.x * inv, ac3.y * inv, ac3.z * inv, ac3.w * inv};
    float4 o4 = {ac4.x * inv, ac4.y * inv, ac4.z * inv, ac4.w * inv};
    op[0] = o0; op[1] = o1; op[2] = o2; op[3] = o3; op[4] = o4;
}

extern "C" void kernel_launch(void* const* d_in, const int* in_sizes, int n_in,
                              void* d_out, int out_size, void* d_ws, size_t ws_size,
                              hipStream_t stream) {
    (void)in_sizes; (void)n_in; (void)out_size; (void)ws_size;
    const float* x      = (const float*)d_in[0];
    const float* eattr  = (const float*)d_in[1];
    const float* cheb_w = (const float*)d_in[2];
    const float* cheb_b = (const float*)d_in[3];
    const float* ee_w   = (const float*)d_in[4];
    const float* ee_b   = (const float*)d_in[5];
    const float* mlp_w1 = (const float*)d_in[6];
    const float* mlp_b1 = (const float*)d_in[7];
    const float* mlp_w2 = (const float*)d_in[8];
    const float* mlp_b2 = (const float*)d_in[9];
    const float* root_w = (const float*)d_in[10];
    const float* conv_b = (const float*)d_in[11];
    const float* ln_g   = (const float*)d_in[12];
    const float* ln_b   = (const float*)d_in[13];
    const float* ain_w  = (const float*)d_in[14];
    const float* ain_b  = (const float*)d_in[15];
    const float* aow    = (const float*)d_in[16];
    const float* aob    = (const float*)d_in[17];
    const float* ffw1   = (const float*)d_in[18];
    const float* ffb1   = (const float*)d_in[19];
    const float* ffw2   = (const float*)d_in[20];
    const float* ffb2   = (const float*)d_in[21];
    const float* t1g    = (const float*)d_in[22];
    const float* t1b    = (const float*)d_in[23];
    const float* t2g    = (const float*)d_in[24];
    const float* t2b    = (const float*)d_in[25];
    const float* lin_w  = (const float*)d_in[26];
    const float* lin_b  = (const float*)d_in[27];
    const int* ei       = (const int*)d_in[29];

    char* w = (char*)d_ws;
    size_t off = 0;
    auto alloc = [&](size_t bytes) -> void* {
        void* p = w + off;
        off += (bytes + 255) & ~(size_t)255;
        return p;
    };
    bf16*  bpk   = (bf16*)alloc((size_t)NLAY * 128 * KTOT * 2);
    float* h     = (float*)alloc((size_t)NND * NH * 4);
    bf16*  zA    = (bf16*)alloc((size_t)NPAD * NH * 2);
    bf16*  zB    = (bf16*)alloc((size_t)NPAD * NH * 2);
    float* tbuf  = (float*)alloc((size_t)NPAD * DD * 4);
    float* qkvC  = (float*)alloc((size_t)NPAD * QKVP * 4);
    float* abuf  = (float*)alloc((size_t)NPAD * DD * 4);
    float* f1    = (float*)alloc((size_t)NPAD * FFD * 4);
    int*   deg   = (int*)alloc((size_t)NND * 4);
    int*   csrs  = (int*)alloc((size_t)NND * CSTR * 4);
    float* csrw  = (float*)alloc((size_t)NND * CSTR * 10 * 4);
    bf16*  bqkv  = (bf16*)alloc((size_t)TLAY * QKVP * DD * 2);
    bf16*  bproj = (bf16*)alloc((size_t)TLAY * PRJP * DD * 2);
    bf16*  bff1  = (bf16*)alloc((size_t)TLAY * FFD * DD * 2);
    bf16*  bff2  = (bf16*)alloc((size_t)TLAY * PRJP * FFD * 2);
    float* tbias = (float*)alloc((size_t)TLAY * 1152 * 4);

    k_setup<<<SB_TOT, 256, 0, stream>>>(x, cheb_w, cheb_b, zA, zB,
                                        eattr, ee_w, ee_b, mlp_w1, mlp_b1,
                                        mlp_w2, mlp_b2, root_w, bpk,
                                        ei, deg, csrs, csrw,
                                        ain_w, aow, ffw1, ffw2,
                                        ain_b, aob, ffb1, ffb2,
                                        bqkv, bproj, bff1, bff2, tbias);

    // --- 10 NNConv layers: ONE dispatch each, 1024-thread blocks ---
    bf16* zcur = zA;
    bf16* znxt = zB;
    for (int l = 0; l < NLAY; ++l) {
        k_layer<<<NPAD / 16, 1024, 0, stream>>>(zcur, h, bpk + (size_t)l * 128 * KTOT,
                                                conv_b, ln_g, ln_b, znxt, tbuf,
                                                deg, csrs, csrw, l);
        bf16* tmp = zcur; zcur = znxt; znxt = tmp;
    }

    // --- transformer encoder: qkv0, then {attn, plnA(+ffn1), plnB(+qkv_next | final)} ---
    k_gmm<<<dim3(QKVP / 64, 14), 256, 0, stream>>>(tbuf, bqkv, tbias, qkvC, 5, DD, QKVP, 0);
    for (int tl = 0; tl < TLAY; ++tl) {
        const float* bb = tbias + (size_t)tl * 1152;
        k_attn<<<dim3(BSZ * THD, 2), 64, 0, stream>>>(qkvC, abuf);
        k_pln<<<NPAD / 16, 512, 0, stream>>>(abuf, bproj + (size_t)tl * PRJP * DD, bb + 512,
                                             5, DD, tbuf,
                                             t1g + (size_t)tl * DD, t1b + (size_t)tl * DD,
                                             1, bff1 + (size_t)tl * FFD * DD, bb + 704, f1,
                                             nullptr, nullptr, nullptr);
        int last = (tl == TLAY - 1);
        k_pln<<<NPAD / 16, 512, 0, stream>>>(f1, bff2 + (size_t)tl * PRJP * FFD, bb + 960,
                                             8, FFD, tbuf,
                                             t2g + (size_t)tl * DD, t2b + (size_t)tl * DD,
                                             last ? 0 : 2,
                                             last ? nullptr : bqkv + (size_t)(tl + 1) * QKVP * DD,
                                             last ? nullptr : tbias + (size_t)(tl + 1) * 1152,
                                             last ? nullptr : qkvC,
                                             last ? lin_w : nullptr,
                                             last ? lin_b : nullptr,
                                             last ? (float*)d_out : nullptr);
    }
}